// Round 1
// baseline (368.291 us; speedup 1.0000x reference)
//
#include <hip/hip_runtime.h>

// ---------------- constants ----------------
#define D_MODEL 768
#define D_INNER 1536
#define NXZ     3072   // 2*D_INNER
#define BATCH   2
#define SEQ     8192
#define MTOT    (BATCH*SEQ)   // 16384
#define WARM    64            // 0.9^64 ~ 1.2e-3; output-level error ~1e-6 << 3.5e-4 threshold

typedef _Float16 v8h __attribute__((ext_vector_type(8)));
typedef _Float16 v4h __attribute__((ext_vector_type(4)));
typedef float    v4f __attribute__((ext_vector_type(4)));
typedef _Float16 f16;

// ---------------- prep: f32 -> f16 convert ----------------
__global__ void k_cvt(const float* __restrict__ in, f16* __restrict__ out, int n4) {
  int i = blockIdx.x * blockDim.x + threadIdx.x;
  if (i < n4) {
    float4 v = reinterpret_cast<const float4*>(in)[i];
    v4h o;
    o[0] = (f16)v.x; o[1] = (f16)v.y; o[2] = (f16)v.z; o[3] = (f16)v.w;
    reinterpret_cast<v4h*>(out)[i] = o;
  }
}

// ---------------- prep: transpose (R,C) f32 -> (C,R) f16 ----------------
__global__ void k_transpose_cvt(const float* __restrict__ in, f16* __restrict__ out,
                                int R, int C) {
  __shared__ float tile[32][33];
  int c0 = blockIdx.x * 32, r0 = blockIdx.y * 32;
  int tx = threadIdx.x, ty = threadIdx.y;   // 32 x 8
#pragma unroll
  for (int i = 0; i < 32; i += 8)
    tile[ty + i][tx] = in[(long)(r0 + ty + i) * C + (c0 + tx)];
  __syncthreads();
#pragma unroll
  for (int i = 0; i < 32; i += 8)
    out[(long)(c0 + ty + i) * R + (r0 + tx)] = (f16)tile[tx][ty + i];
}

// async global->LDS, 16B per lane, dest = wave-uniform base + lane*16
__device__ __forceinline__ void gload_lds16(const void* g, void* l) {
  __builtin_amdgcn_global_load_lds((const __attribute__((address_space(1))) void*)g,
                                   (__attribute__((address_space(3))) void*)l, 16, 0, 0);
}

// ---------------- 256x256xBK64 8-phase pipelined MFMA GEMM ----------------
// C = A[M,K] * Bt[N,K]^T + bias.
// 512 threads = 8 waves (2M x 4N); per-wave C = 128x64 (acc[8][4] v4f).
// LDS 128 KB: [A|B][buf 2][kstep 2][16 blocks][1KB]. Each 1KB block holds 16
// rows x 32 f16 in chunk-major order: offset = (lane>>4)*256B + (lane&15)*16B
// = lane*16B. So gload_lds (linear lane*16 dest) and the MFMA fragment read
// (base + lane*16) use the IDENTICAL layout -> conflict-free (2 lanes/bank),
// no swizzle math.
// Schedule (per K-tile t, 4 phases; staging 6 half-tiles ahead, vmcnt(4)
// once per tile -- never drained to 0 in steady state):
//   ph0: rdB(k0) rdA(k0,mi0-3)  stage t+1.A k1   BAR lgkm MFMA BAR
//   ph1:          rdA(k0,mi4-7) stage t+1.B k1   BAR lgkm MFMA BAR
//   ph2: rdB(k1) rdA(k1,mi0-3)  stage t+2.A k0   BAR lgkm MFMA BAR
//   ph3:          rdA(k1,mi4-7) stage t+2.B k0  vmcnt(4) BAR lgkm MFMA BAR
// k0-regions of the current buffer are dead after ph1 (their last ds_read),
// so t+2's k0 staging at ph2/ph3 into the SAME buffer is safe; t+1 parts go
// into the other buffer whose readers finished at t-1 ph3. vmcnt(4) at ph3
// leaves exactly the 4 loads of t+2.{Ak0,Bk0} in flight and forces tile t+1
// complete before its first read.
template <bool F16OUT>
__launch_bounds__(512, 2)
__global__ void k_gemm256(const f16* __restrict__ A, const f16* __restrict__ Bt,
                          const float* __restrict__ bias, void* __restrict__ Cv,
                          int M, int N, int K) {
  __shared__ f16 sA[2][2][8192];   // [buf][kstep][16KB/2B] = 64 KB
  __shared__ f16 sB[2][2][8192];   // 64 KB
  const int tid  = threadIdx.x;
  const int lane = tid & 63;
  const int wave = tid >> 6;       // 0..7
  const int wm   = wave >> 2;      // 0..1  (rows wm*128)
  const int wn   = wave & 3;       // 0..3  (cols wn*64)
  const int m16  = lane & 15;
  const int quad = lane >> 4;

  // XCD-aware swizzle (T1): nwg is divisible by 8 for both GEMMs here
  const int nwg  = gridDim.x * gridDim.y;
  const int orig = blockIdx.y * gridDim.x + blockIdx.x;
  const int swz  = (orig & 7) * (nwg >> 3) + (orig >> 3);
  const int bx   = swz % gridDim.x;
  const int by   = swz / gridDim.x;
  const long m0  = (long)by * 256;
  const long n0  = (long)bx * 256;

  // staging source: wave w, load q -> 1KB block q*8+w = rows q*128+w*16..+15;
  // lane: row += lane&15, 16B col chunk = (lane>>4)*8 f16 within the k-slice
  const int  srow = wave * 16 + m16;
  const int  scol = quad * 8;
  const f16* aS0 = A  + (m0 + srow) * (long)K + scol;
  const f16* aS1 = aS0 + (long)128 * K;
  const f16* bS0 = Bt + (n0 + srow) * (long)K + scol;
  const f16* bS1 = bS0 + (long)128 * K;

#define STG_A(b_, kp_, ko_)                                        \
  gload_lds16(aS0 + (ko_), &sA[b_][kp_][wave << 9]);               \
  gload_lds16(aS1 + (ko_), &sA[b_][kp_][(8 + wave) << 9]);
#define STG_B(b_, kp_, ko_)                                        \
  gload_lds16(bS0 + (ko_), &sB[b_][kp_][wave << 9]);               \
  gload_lds16(bS1 + (ko_), &sB[b_][kp_][(8 + wave) << 9]);
#define RD_A(b_, kp_, miB_)                                                          \
  fa[0] = *(const v8h*)&sA[b_][kp_][(((wm << 3) + (miB_) + 0) << 9) + (lane << 3)];  \
  fa[1] = *(const v8h*)&sA[b_][kp_][(((wm << 3) + (miB_) + 1) << 9) + (lane << 3)];  \
  fa[2] = *(const v8h*)&sA[b_][kp_][(((wm << 3) + (miB_) + 2) << 9) + (lane << 3)];  \
  fa[3] = *(const v8h*)&sA[b_][kp_][(((wm << 3) + (miB_) + 3) << 9) + (lane << 3)];
#define RD_B(b_, kp_)                                                                \
  fb[0] = *(const v8h*)&sB[b_][kp_][(((wn << 2) + 0) << 9) + (lane << 3)];           \
  fb[1] = *(const v8h*)&sB[b_][kp_][(((wn << 2) + 1) << 9) + (lane << 3)];           \
  fb[2] = *(const v8h*)&sB[b_][kp_][(((wn << 2) + 2) << 9) + (lane << 3)];           \
  fb[3] = *(const v8h*)&sB[b_][kp_][(((wn << 2) + 3) << 9) + (lane << 3)];
#define MMQ(miB_, i_)                                                                              \
  acc[(miB_)+i_][0] = __builtin_amdgcn_mfma_f32_16x16x32_f16(fa[i_], fb[0], acc[(miB_)+i_][0], 0, 0, 0); \
  acc[(miB_)+i_][1] = __builtin_amdgcn_mfma_f32_16x16x32_f16(fa[i_], fb[1], acc[(miB_)+i_][1], 0, 0, 0); \
  acc[(miB_)+i_][2] = __builtin_amdgcn_mfma_f32_16x16x32_f16(fa[i_], fb[2], acc[(miB_)+i_][2], 0, 0, 0); \
  acc[(miB_)+i_][3] = __builtin_amdgcn_mfma_f32_16x16x32_f16(fa[i_], fb[3], acc[(miB_)+i_][3], 0, 0, 0);
#define MM(miB_)                                          \
  __builtin_amdgcn_s_barrier();                           \
  asm volatile("s_waitcnt lgkmcnt(0)" ::: "memory");      \
  __builtin_amdgcn_sched_barrier(0);                      \
  __builtin_amdgcn_s_setprio(1);                          \
  MMQ(miB_, 0) MMQ(miB_, 1) MMQ(miB_, 2) MMQ(miB_, 3)     \
  __builtin_amdgcn_s_setprio(0);                          \
  __builtin_amdgcn_sched_barrier(0);                      \
  __builtin_amdgcn_s_barrier();

  v4f acc[8][4];
#pragma unroll
  for (int i = 0; i < 8; ++i)
#pragma unroll
    for (int j = 0; j < 4; ++j)
#pragma unroll
      for (int r = 0; r < 4; ++r) acc[i][j][r] = 0.f;
  v8h fa[4], fb[4];

  const int T = K >> 6;   // K / 64 tiles (K=768 -> 12, K=1536 -> 24)

  // prologue: stage tile0 {Ak0,Bk0,Ak1,Bk1} + tile1 {Ak0,Bk0} (12 loads/wave)
  STG_A(0, 0, 0)  STG_B(0, 0, 0)
  STG_A(0, 1, 32) STG_B(0, 1, 32)
  STG_A(1, 0, 64) STG_B(1, 0, 64)
  asm volatile("s_waitcnt vmcnt(4)" ::: "memory");   // tile0 fully landed
  __builtin_amdgcn_s_barrier();

  int t = 0;
#pragma unroll 1
  for (; t < T - 2; ++t) {
    const int b  = t & 1, nb = b ^ 1;
    const int k1 = (t + 1) * 64 + 32;   // tile t+1, kstep1
    const int k2 = (t + 2) * 64;        // tile t+2, kstep0
    RD_B(b, 0) RD_A(b, 0, 0) STG_A(nb, 1, k1) MM(0)
    RD_A(b, 0, 4)            STG_B(nb, 1, k1) MM(4)
    RD_B(b, 1) RD_A(b, 1, 0) STG_A(b, 0, k2)  MM(0)
    RD_A(b, 1, 4)            STG_B(b, 0, k2)
    asm volatile("s_waitcnt vmcnt(4)" ::: "memory");  // tile t+1 fully landed
    MM(4)
  }
  { // tile T-2: only tile T-1's kstep1 remains to stage; drain at ph3
    const int b  = t & 1, nb = b ^ 1;
    const int k1 = (t + 1) * 64 + 32;
    RD_B(b, 0) RD_A(b, 0, 0) STG_A(nb, 1, k1) MM(0)
    RD_A(b, 0, 4)            STG_B(nb, 1, k1) MM(4)
    RD_B(b, 1) RD_A(b, 1, 0)                  MM(0)
    RD_A(b, 1, 4)
    asm volatile("s_waitcnt vmcnt(0)" ::: "memory");
    MM(4)
    ++t;
  }
  { // tile T-1: no staging
    const int b = t & 1;
    RD_B(b, 0) RD_A(b, 0, 0) MM(0)
    RD_A(b, 0, 4)            MM(4)
    RD_B(b, 1) RD_A(b, 1, 0) MM(0)
    RD_A(b, 1, 4)            MM(4)
  }

  // epilogue: D layout col = lane&15, row = quad*4 + r (verified convention)
#pragma unroll
  for (int i = 0; i < 8; ++i) {
#pragma unroll
    for (int j = 0; j < 4; ++j) {
      const long n = n0 + wn * 64 + j * 16 + m16;
      const float bv = bias[n];
#pragma unroll
      for (int r = 0; r < 4; ++r) {
        const long m = m0 + wm * 128 + i * 16 + quad * 4 + r;
        float v = acc[i][j][r] + bv;
        if (F16OUT) ((f16*)Cv)[m * N + n] = (f16)v;
        else        ((float*)Cv)[m * N + n] = v;
      }
    }
  }
#undef STG_A
#undef STG_B
#undef RD_A
#undef RD_B
#undef MMQ
#undef MM
}

// ---------------- conv4 + SiLU + EMA scan + gate (LDS-staged) ----------------
__global__ void k_conv_scan(const f16* __restrict__ xz, const float* __restrict__ conv_w,
                            const float* __restrict__ conv_b, const float* __restrict__ Dp_,
                            f16* __restrict__ y) {
  __shared__ f16 xs[64][256];   // 32 KB
  __shared__ f16 zs[64][256];   // 32 KB
  const int tid = threadIdx.x;
  const int c0  = blockIdx.y * 256;
  const int c   = c0 + tid;
  const int b   = blockIdx.z;
  const int t0  = blockIdx.x * 128;
  const float w0 = conv_w[c * 4 + 0], w1 = conv_w[c * 4 + 1];
  const float w2 = conv_w[c * 4 + 2], w3 = conv_w[c * 4 + 3];
  const float cb = conv_b[c], Dp = Dp_[c];
  const long mb = (long)b * SEQ;

  float xm3 = 0.f, xm2 = 0.f, xm1 = 0.f, h = 0.f;
  const int ts = t0 - WARM;   // panel-0 start; < 0 only for blockIdx.x==0
  if (t0 > 0) {
    xm3 = (float)xz[(mb + ts - 3) * (long)NXZ + c];
    xm2 = (float)xz[(mb + ts - 2) * (long)NXZ + c];
    xm1 = (float)xz[(mb + ts - 1) * (long)NXZ + c];
  }

  for (int p = 0; p < 3; ++p) {
    const int tp = ts + p * 64;         // block-uniform
    __syncthreads();                    // protect previous panel before overwrite
    if (tp >= 0) {
#pragma unroll
      for (int j = 0; j < 8; ++j) {
        const int idx = j * 256 + tid, row = idx >> 5, col = (idx & 31) << 3;
        *(v8h*)&xs[row][col] = *(const v8h*)&xz[(mb + tp + row) * (long)NXZ + c0 + col];
      }
      if (p > 0) {
#pragma unroll
        for (int j = 0; j < 8; ++j) {
          const int idx = j * 256 + tid, row = idx >> 5, col = (idx & 31) << 3;
          *(v8h*)&zs[row][col] = *(const v8h*)&xz[(mb + tp + row) * (long)NXZ + D_INNER + c0 + col];
        }
      }
    }
    __syncthreads();
    if (tp < 0) continue;               // t<0: zero left-pad, h stays 0 (skip)
    if (p == 0) {
      // warm-up: EMA only, no output
      for (int tl = 0; tl < 64; ++tl) {
        float xt = (float)xs[tl][tid];
        float u = w0 * xm3 + w1 * xm2 + w2 * xm1 + w3 * xt + cb;
        h = 0.9f * h + 0.1f * (u / (1.f + __expf(-u)));
        xm3 = xm2; xm2 = xm1; xm1 = xt;
      }
    } else {
      f16* yo = y + (mb + tp) * (long)D_INNER + c;
      for (int tl = 0; tl < 64; ++tl) {
        float xt = (float)xs[tl][tid];
        float u = w0 * xm3 + w1 * xm2 + w2 * xm1 + w3 * xt + cb;
        float v = u / (1.f + __expf(-u));
        h = 0.9f * h + 0.1f * v;
        float zv = (float)zs[tl][tid];
        float g = zv / (1.f + __expf(-zv));
        yo[(long)tl * D_INNER] = (f16)((v * Dp + h) * g);
        xm3 = xm2; xm2 = xm1; xm1 = xt;
      }
    }
  }
}

// ---------------- launch ----------------
extern "C" void kernel_launch(void* const* d_in, const int* in_sizes, int n_in,
                              void* d_out, int out_size, void* d_ws, size_t ws_size,
                              hipStream_t stream) {
  const float* x       = (const float*)d_in[0];
  const float* in_w    = (const float*)d_in[1];
  const float* in_b    = (const float*)d_in[2];
  const float* conv_w  = (const float*)d_in[3];
  const float* conv_b  = (const float*)d_in[4];
  // d_in[5..8] (xp_w, xp_b, dt_w, dt_b) are dead code in the reference
  const float* D_param = (const float*)d_in[9];
  const float* out_w   = (const float*)d_in[10];
  const float* out_b   = (const float*)d_in[11];
  float* out = (float*)d_out;

  char* p = (char*)d_ws;
  f16* xb    = (f16*)p; p += (size_t)MTOT * D_MODEL * 2;   // 25.2 MB
  f16* wInT  = (f16*)p; p += (size_t)NXZ * D_MODEL * 2;    //  4.7 MB
  f16* wOutT = (f16*)p; p += (size_t)D_MODEL * D_INNER * 2;//  2.4 MB
  f16* xzb   = (f16*)p; p += (size_t)MTOT * NXZ * 2;       // 100.7 MB ([m][n])
  f16* yb    = (f16*)p; p += (size_t)MTOT * D_INNER * 2;   // 50.3 MB

  // prep
  k_cvt<<<(MTOT * D_MODEL / 4 + 255) / 256, 256, 0, stream>>>(x, xb, MTOT * D_MODEL / 4);
  k_transpose_cvt<<<dim3(NXZ / 32, D_MODEL / 32), dim3(32, 8), 0, stream>>>(in_w, wInT, D_MODEL, NXZ);
  k_transpose_cvt<<<dim3(D_MODEL / 32, D_INNER / 32), dim3(32, 8), 0, stream>>>(out_w, wOutT, D_INNER, D_MODEL);

  // xz = x @ in_w + in_b   (f16, [m][n]); grid 12x64 = 768 blocks (%8==0)
  k_gemm256<true><<<dim3(NXZ / 256, MTOT / 256), 512, 0, stream>>>(xb, wInT, in_b, xzb, MTOT, NXZ, D_MODEL);

  // conv + silu + EMA scan + gate -> y (f16, [m][c])
  k_conv_scan<<<dim3(SEQ / 128, D_INNER / 256, BATCH), 256, 0, stream>>>(xzb, conv_w, conv_b, D_param, yb);

  // out = y @ out_w + out_b  (f32, [m][n]); grid 3x64 = 192 blocks (%8==0)
  k_gemm256<false><<<dim3(D_MODEL / 256, MTOT / 256), 512, 0, stream>>>(yb, wOutT, out_b, out, MTOT, D_MODEL, D_INNER);
}

// Round 2
// 339.259 us; speedup vs baseline: 1.0856x; 1.0856x over previous
//
#include <hip/hip_runtime.h>

// ---------------- constants ----------------
#define D_MODEL 768
#define D_INNER 1536
#define NXZ     3072   // 2*D_INNER
#define BATCH   2
#define SEQ     8192
#define MTOT    (BATCH*SEQ)   // 16384
#define WARM    64            // 0.9^64 ~ 1.2e-3; output-level error ~1e-6 << 3.5e-4 threshold

typedef _Float16 v8h __attribute__((ext_vector_type(8)));
typedef _Float16 v4h __attribute__((ext_vector_type(4)));
typedef float    v4f __attribute__((ext_vector_type(4)));
typedef _Float16 f16;

// ---------------- prep: f32 -> f16 convert ----------------
__global__ void k_cvt(const float* __restrict__ in, f16* __restrict__ out, int n4) {
  int i = blockIdx.x * blockDim.x + threadIdx.x;
  if (i < n4) {
    float4 v = reinterpret_cast<const float4*>(in)[i];
    v4h o;
    o[0] = (f16)v.x; o[1] = (f16)v.y; o[2] = (f16)v.z; o[3] = (f16)v.w;
    reinterpret_cast<v4h*>(out)[i] = o;
  }
}

// ---------------- prep: transpose (R,C) f32 -> (C,R) f16 ----------------
__global__ void k_transpose_cvt(const float* __restrict__ in, f16* __restrict__ out,
                                int R, int C) {
  __shared__ float tile[32][33];
  int c0 = blockIdx.x * 32, r0 = blockIdx.y * 32;
  int tx = threadIdx.x, ty = threadIdx.y;   // 32 x 8
#pragma unroll
  for (int i = 0; i < 32; i += 8)
    tile[ty + i][tx] = in[(long)(r0 + ty + i) * C + (c0 + tx)];
  __syncthreads();
#pragma unroll
  for (int i = 0; i < 32; i += 8)
    out[(long)(c0 + ty + i) * R + (r0 + tx)] = (f16)tile[tx][ty + i];
}

// async global->LDS, 16B per lane, dest = wave-uniform base + lane*16
__device__ __forceinline__ void gload_lds16(const void* g, void* l) {
  __builtin_amdgcn_global_load_lds((const __attribute__((address_space(1))) void*)g,
                                   (__attribute__((address_space(3))) void*)l, 16, 0, 0);
}

// ---------------- MFMA GEMM: C = A[M,K] * Bt[N,K]^T + bias ----------------
// R2 structure (proven 666 TF) with BK=64: halves the per-K-step fixed cost
// (2 barriers + vmcnt/lgkm drain) while doubling MFMA work per step.
// LDS rows are 128B (64 f16, 8x 16B chunks). Swizzle: phys_chunk =
// logical_chunk ^ (row&7). Stage side: gload_lds dest is linear lane*16
// (row = wave*8+g*32+(lane>>3), phys chunk = lane&7), so the GLOBAL source
// is pre-swizzled: logical chunk = (lane&7)^(lane>>3). Read side: lane
// (m16,quad) wants logical chunk quad (k-half 0) / quad^4 (k-half 1) of row
// with row&7 = m16&7 -> phys col = ((quad^(m16&7))<<3) and ^32. Uniform 8
// lanes per 16B column -> conflict-free.
template <bool F16OUT>
__launch_bounds__(256, 2)
__global__ void k_gemm_bt(const f16* __restrict__ A, const f16* __restrict__ Bt,
                          const float* __restrict__ bias, void* __restrict__ Cv,
                          int M, int N, int K) {
  __shared__ f16 As[128][64];   // 16 KB
  __shared__ f16 Bs[128][64];   // 16 KB
  const int tid  = threadIdx.x;
  const int lane = tid & 63;
  const int wave = tid >> 6;
  const int wm   = (wave >> 1) * 64;
  const int wn   = (wave & 1) * 64;
  const int m16  = lane & 15;
  const int quad = lane >> 4;
  const long m0 = (long)blockIdx.y * 128;
  const long n0 = (long)blockIdx.x * 128;

  v4f acc[4][4];
#pragma unroll
  for (int i = 0; i < 4; i++)
#pragma unroll
    for (int j = 0; j < 4; j++)
#pragma unroll
      for (int r = 0; r < 4; r++) acc[i][j][r] = 0.f;

  // staging: lane l covers row wave*8 + (l>>3) (+ g*32), global col chunk
  // pre-swizzled (l&7)^(l>>3); 4 gloads per matrix per wave per 64-K step
  const int  srow = wave * 8 + (lane >> 3);
  const int  gcol = ((lane & 7) ^ (lane >> 3)) << 3;
  const f16* Ag = A  + (m0 + srow) * (long)K + gcol;
  const f16* Bg = Bt + (n0 + srow) * (long)K + gcol;
  f16* AsD0 = &As[wave * 8][0];
  f16* AsD1 = &As[wave * 8 + 32][0];
  f16* AsD2 = &As[wave * 8 + 64][0];
  f16* AsD3 = &As[wave * 8 + 96][0];
  f16* BsD0 = &Bs[wave * 8][0];
  f16* BsD1 = &Bs[wave * 8 + 32][0];
  f16* BsD2 = &Bs[wave * 8 + 64][0];
  f16* BsD3 = &Bs[wave * 8 + 96][0];

  const int c0q = ((quad ^ (m16 & 7)) << 3);   // phys col (f16), k-half 0
  const int c1q = c0q ^ 32;                    // k-half 1 (logical chunk ^4)

  for (int k0 = 0; k0 < K; k0 += 64) {
    gload_lds16(Ag,                AsD0);
    gload_lds16(Ag + (long)32 * K, AsD1);
    gload_lds16(Ag + (long)64 * K, AsD2);
    gload_lds16(Ag + (long)96 * K, AsD3);
    gload_lds16(Bg,                BsD0);
    gload_lds16(Bg + (long)32 * K, BsD1);
    gload_lds16(Bg + (long)64 * K, BsD2);
    gload_lds16(Bg + (long)96 * K, BsD3);
    Ag += 64; Bg += 64;
    __syncthreads();                // drains vmcnt -> staged tile visible
    v8h af[4], bfr[4];
    // ---- k-half 0 ----
#pragma unroll
    for (int i = 0; i < 4; i++) af[i]  = *(const v8h*)&As[wm + i * 16 + m16][c0q];
#pragma unroll
    for (int j = 0; j < 4; j++) bfr[j] = *(const v8h*)&Bs[wn + j * 16 + m16][c0q];
#pragma unroll
    for (int i = 0; i < 4; i++)
#pragma unroll
      for (int j = 0; j < 4; j++)
        acc[i][j] = __builtin_amdgcn_mfma_f32_16x16x32_f16(af[i], bfr[j], acc[i][j], 0, 0, 0);
    // ---- k-half 1 ----
#pragma unroll
    for (int i = 0; i < 4; i++) af[i]  = *(const v8h*)&As[wm + i * 16 + m16][c1q];
#pragma unroll
    for (int j = 0; j < 4; j++) bfr[j] = *(const v8h*)&Bs[wn + j * 16 + m16][c1q];
#pragma unroll
    for (int i = 0; i < 4; i++)
#pragma unroll
      for (int j = 0; j < 4; j++)
        acc[i][j] = __builtin_amdgcn_mfma_f32_16x16x32_f16(af[i], bfr[j], acc[i][j], 0, 0, 0);
    __syncthreads();                // protect LDS before next stage
  }

#pragma unroll
  for (int i = 0; i < 4; i++) {
#pragma unroll
    for (int j = 0; j < 4; j++) {
      const long n = n0 + wn + j * 16 + m16;
      const float bv = bias[n];
#pragma unroll
      for (int r = 0; r < 4; r++) {
        const long m = m0 + wm + i * 16 + quad * 4 + r;
        float v = acc[i][j][r] + bv;
        if (F16OUT) ((f16*)Cv)[m * N + n] = (f16)v;
        else        ((float*)Cv)[m * N + n] = v;
      }
    }
  }
}

// ---------------- conv4 + SiLU + EMA scan + gate (LDS-staged) ----------------
__global__ void k_conv_scan(const f16* __restrict__ xz, const float* __restrict__ conv_w,
                            const float* __restrict__ conv_b, const float* __restrict__ Dp_,
                            f16* __restrict__ y) {
  __shared__ f16 xs[64][256];   // 32 KB
  __shared__ f16 zs[64][256];   // 32 KB
  const int tid = threadIdx.x;
  const int c0  = blockIdx.y * 256;
  const int c   = c0 + tid;
  const int b   = blockIdx.z;
  const int t0  = blockIdx.x * 128;
  const float w0 = conv_w[c * 4 + 0], w1 = conv_w[c * 4 + 1];
  const float w2 = conv_w[c * 4 + 2], w3 = conv_w[c * 4 + 3];
  const float cb = conv_b[c], Dp = Dp_[c];
  const long mb = (long)b * SEQ;

  float xm3 = 0.f, xm2 = 0.f, xm1 = 0.f, h = 0.f;
  const int ts = t0 - WARM;   // panel-0 start; < 0 only for blockIdx.x==0
  if (t0 > 0) {
    xm3 = (float)xz[(mb + ts - 3) * (long)NXZ + c];
    xm2 = (float)xz[(mb + ts - 2) * (long)NXZ + c];
    xm1 = (float)xz[(mb + ts - 1) * (long)NXZ + c];
  }

  for (int p = 0; p < 3; ++p) {
    const int tp = ts + p * 64;         // block-uniform
    __syncthreads();                    // protect previous panel before overwrite
    if (tp >= 0) {
#pragma unroll
      for (int j = 0; j < 8; ++j) {
        const int idx = j * 256 + tid, row = idx >> 5, col = (idx & 31) << 3;
        *(v8h*)&xs[row][col] = *(const v8h*)&xz[(mb + tp + row) * (long)NXZ + c0 + col];
      }
      if (p > 0) {
#pragma unroll
        for (int j = 0; j < 8; ++j) {
          const int idx = j * 256 + tid, row = idx >> 5, col = (idx & 31) << 3;
          *(v8h*)&zs[row][col] = *(const v8h*)&xz[(mb + tp + row) * (long)NXZ + D_INNER + c0 + col];
        }
      }
    }
    __syncthreads();
    if (tp < 0) continue;               // t<0: zero left-pad, h stays 0 (skip)
    if (p == 0) {
      // warm-up: EMA only, no output
      for (int tl = 0; tl < 64; ++tl) {
        float xt = (float)xs[tl][tid];
        float u = w0 * xm3 + w1 * xm2 + w2 * xm1 + w3 * xt + cb;
        h = 0.9f * h + 0.1f * (u / (1.f + __expf(-u)));
        xm3 = xm2; xm2 = xm1; xm1 = xt;
      }
    } else {
      f16* yo = y + (mb + tp) * (long)D_INNER + c;
      for (int tl = 0; tl < 64; ++tl) {
        float xt = (float)xs[tl][tid];
        float u = w0 * xm3 + w1 * xm2 + w2 * xm1 + w3 * xt + cb;
        float v = u / (1.f + __expf(-u));
        h = 0.9f * h + 0.1f * v;
        float zv = (float)zs[tl][tid];
        float g = zv / (1.f + __expf(-zv));
        yo[(long)tl * D_INNER] = (f16)((v * Dp + h) * g);
        xm3 = xm2; xm2 = xm1; xm1 = xt;
      }
    }
  }
}

// ---------------- launch ----------------
extern "C" void kernel_launch(void* const* d_in, const int* in_sizes, int n_in,
                              void* d_out, int out_size, void* d_ws, size_t ws_size,
                              hipStream_t stream) {
  const float* x       = (const float*)d_in[0];
  const float* in_w    = (const float*)d_in[1];
  const float* in_b    = (const float*)d_in[2];
  const float* conv_w  = (const float*)d_in[3];
  const float* conv_b  = (const float*)d_in[4];
  // d_in[5..8] (xp_w, xp_b, dt_w, dt_b) are dead code in the reference
  const float* D_param = (const float*)d_in[9];
  const float* out_w   = (const float*)d_in[10];
  const float* out_b   = (const float*)d_in[11];
  float* out = (float*)d_out;

  char* p = (char*)d_ws;
  f16* xb    = (f16*)p; p += (size_t)MTOT * D_MODEL * 2;   // 25.2 MB
  f16* wInT  = (f16*)p; p += (size_t)NXZ * D_MODEL * 2;    //  4.7 MB
  f16* wOutT = (f16*)p; p += (size_t)D_MODEL * D_INNER * 2;//  2.4 MB
  f16* xzb   = (f16*)p; p += (size_t)MTOT * NXZ * 2;       // 100.7 MB ([m][n])
  f16* yb    = (f16*)p; p += (size_t)MTOT * D_INNER * 2;   // 50.3 MB

  // prep
  k_cvt<<<(MTOT * D_MODEL / 4 + 255) / 256, 256, 0, stream>>>(x, xb, MTOT * D_MODEL / 4);
  k_transpose_cvt<<<dim3(NXZ / 32, D_MODEL / 32), dim3(32, 8), 0, stream>>>(in_w, wInT, D_MODEL, NXZ);
  k_transpose_cvt<<<dim3(D_MODEL / 32, D_INNER / 32), dim3(32, 8), 0, stream>>>(out_w, wOutT, D_INNER, D_MODEL);

  // xz = x @ in_w + in_b   (f16, [m][n])
  k_gemm_bt<true><<<dim3(NXZ / 128, MTOT / 128), 256, 0, stream>>>(xb, wInT, in_b, xzb, MTOT, NXZ, D_MODEL);

  // conv + silu + EMA scan + gate -> y (f16, [m][c])
  k_conv_scan<<<dim3(SEQ / 128, D_INNER / 256, BATCH), 256, 0, stream>>>(xzb, conv_w, conv_b, D_param, yb);

  // out = y @ out_w + out_b  (f32, [m][n])
  k_gemm_bt<false><<<dim3(D_MODEL / 128, MTOT / 128), 256, 0, stream>>>(yb, wOutT, out_b, out, MTOT, D_MODEL, D_INNER);
}

// Round 3
// 335.318 us; speedup vs baseline: 1.0983x; 1.0118x over previous
//
#include <hip/hip_runtime.h>

// ---------------- constants ----------------
#define D_MODEL 768
#define D_INNER 1536
#define NXZ     3072   // 2*D_INNER
#define BATCH   2
#define SEQ     8192
#define MTOT    (BATCH*SEQ)   // 16384
#define WARM    64            // 0.9^64 ~ 1.2e-3; output-level error ~1e-6 << 3.5e-4 threshold

typedef _Float16 v8h __attribute__((ext_vector_type(8)));
typedef _Float16 v4h __attribute__((ext_vector_type(4)));
typedef float    v4f __attribute__((ext_vector_type(4)));
typedef _Float16 f16;

// ---------------- prep: f32 -> f16 convert ----------------
__global__ void k_cvt(const float* __restrict__ in, f16* __restrict__ out, int n4) {
  int i = blockIdx.x * blockDim.x + threadIdx.x;
  if (i < n4) {
    float4 v = reinterpret_cast<const float4*>(in)[i];
    v4h o;
    o[0] = (f16)v.x; o[1] = (f16)v.y; o[2] = (f16)v.z; o[3] = (f16)v.w;
    reinterpret_cast<v4h*>(out)[i] = o;
  }
}

// ---------------- prep: transpose (R,C) f32 -> (C,R) f16 ----------------
__global__ void k_transpose_cvt(const float* __restrict__ in, f16* __restrict__ out,
                                int R, int C) {
  __shared__ float tile[32][33];
  int c0 = blockIdx.x * 32, r0 = blockIdx.y * 32;
  int tx = threadIdx.x, ty = threadIdx.y;   // 32 x 8
#pragma unroll
  for (int i = 0; i < 32; i += 8)
    tile[ty + i][tx] = in[(long)(r0 + ty + i) * C + (c0 + tx)];
  __syncthreads();
#pragma unroll
  for (int i = 0; i < 32; i += 8)
    out[(long)(c0 + ty + i) * R + (r0 + tx)] = (f16)tile[tx][ty + i];
}

// async global->LDS, 16B per lane, dest = wave-uniform base + lane*16
__device__ __forceinline__ void gload_lds16(const void* g, void* l) {
  __builtin_amdgcn_global_load_lds((const __attribute__((address_space(1))) void*)g,
                                   (__attribute__((address_space(3))) void*)l, 16, 0, 0);
}

// ---------------- MFMA GEMM: C = A[M,K] * Bt[N,K]^T + bias ----------------
// R2 structure, BM=256 x BN=128 x BK=64 (R3): doubles MFMA work per
// barrier-drain step (64 MFMA/wave/step) against the same per-step fixed
// cost. 256 threads = 4 waves, each owns a 128x64 output (acc[8][4]).
// LDS rows are 128B (64 f16, 8x 16B chunks). Swizzle: phys_chunk =
// logical_chunk ^ (row&7). Stage side: gload_lds dest is linear lane*16
// (row = wave*8 + g*32 + (lane>>3), phys chunk = lane&7), so the GLOBAL
// source is pre-swizzled: logical chunk = (lane&7)^(lane>>3). Read side:
// lane (m16,quad) wants logical chunk quad (k-half 0) / quad^4 (k-half 1)
// of a row with row&7 = m16&7 -> phys col = ((quad^(m16&7))<<3) and ^32.
// Measured 0 bank conflicts with this scheme (R2).
template <bool F16OUT>
__launch_bounds__(256, 2)
__global__ void k_gemm_bt(const f16* __restrict__ A, const f16* __restrict__ Bt,
                          const float* __restrict__ bias, void* __restrict__ Cv,
                          int M, int N, int K) {
  __shared__ f16 As[256][64];   // 32 KB
  __shared__ f16 Bs[128][64];   // 16 KB
  const int tid  = threadIdx.x;
  const int lane = tid & 63;
  const int wave = tid >> 6;
  const int wm   = (wave >> 1) * 128;   // wave row base (2 waves in M)
  const int wn   = (wave & 1) * 64;     // wave col base (2 waves in N)
  const int m16  = lane & 15;
  const int quad = lane >> 4;
  const long m0 = (long)blockIdx.y * 256;
  const long n0 = (long)blockIdx.x * 128;

  v4f acc[8][4];
#pragma unroll
  for (int i = 0; i < 8; i++)
#pragma unroll
    for (int j = 0; j < 4; j++)
#pragma unroll
      for (int r = 0; r < 4; r++) acc[i][j][r] = 0.f;

  // staging: lane l covers row wave*8 + (l>>3) (+ g*32), global col chunk
  // pre-swizzled (l&7)^(l>>3); 8 A-gloads + 4 B-gloads per wave per step
  const int  srow = wave * 8 + (lane >> 3);
  const int  gcol = ((lane & 7) ^ (lane >> 3)) << 3;
  const f16* Ag = A  + (m0 + srow) * (long)K + gcol;
  const f16* Bg = Bt + (n0 + srow) * (long)K + gcol;
  f16* AsW = &As[wave * 8][0];   // wave-uniform dest bases
  f16* BsW = &Bs[wave * 8][0];

  const int c0q = ((quad ^ (m16 & 7)) << 3);   // phys col (f16), k-half 0
  const int c1q = c0q ^ 32;                    // k-half 1 (logical chunk ^4)

  for (int k0 = 0; k0 < K; k0 += 64) {
#pragma unroll
    for (int g = 0; g < 8; ++g)
      gload_lds16(Ag + (long)(g * 32) * K, AsW + g * 32 * 64);
#pragma unroll
    for (int g = 0; g < 4; ++g)
      gload_lds16(Bg + (long)(g * 32) * K, BsW + g * 32 * 64);
    Ag += 64; Bg += 64;
    __syncthreads();                // drains vmcnt -> staged tile visible
    v8h bfr[4], af;
    // ---- k-half 0 ----
#pragma unroll
    for (int j = 0; j < 4; j++) bfr[j] = *(const v8h*)&Bs[wn + j * 16 + m16][c0q];
#pragma unroll
    for (int i = 0; i < 8; i++) {
      af = *(const v8h*)&As[wm + i * 16 + m16][c0q];
#pragma unroll
      for (int j = 0; j < 4; j++)
        acc[i][j] = __builtin_amdgcn_mfma_f32_16x16x32_f16(af, bfr[j], acc[i][j], 0, 0, 0);
    }
    // ---- k-half 1 ----
#pragma unroll
    for (int j = 0; j < 4; j++) bfr[j] = *(const v8h*)&Bs[wn + j * 16 + m16][c1q];
#pragma unroll
    for (int i = 0; i < 8; i++) {
      af = *(const v8h*)&As[wm + i * 16 + m16][c1q];
#pragma unroll
      for (int j = 0; j < 4; j++)
        acc[i][j] = __builtin_amdgcn_mfma_f32_16x16x32_f16(af, bfr[j], acc[i][j], 0, 0, 0);
    }
    __syncthreads();                // protect LDS before next stage
  }

#pragma unroll
  for (int i = 0; i < 8; i++) {
#pragma unroll
    for (int j = 0; j < 4; j++) {
      const long n = n0 + wn + j * 16 + m16;
      const float bv = bias[n];
#pragma unroll
      for (int r = 0; r < 4; r++) {
        const long m = m0 + wm + i * 16 + quad * 4 + r;
        float v = acc[i][j][r] + bv;
        if (F16OUT) ((f16*)Cv)[m * N + n] = (f16)v;
        else        ((float*)Cv)[m * N + n] = v;
      }
    }
  }
}

// ---------------- conv4 + SiLU + EMA scan + gate (LDS-staged) ----------------
__global__ void k_conv_scan(const f16* __restrict__ xz, const float* __restrict__ conv_w,
                            const float* __restrict__ conv_b, const float* __restrict__ Dp_,
                            f16* __restrict__ y) {
  __shared__ f16 xs[64][256];   // 32 KB
  __shared__ f16 zs[64][256];   // 32 KB
  const int tid = threadIdx.x;
  const int c0  = blockIdx.y * 256;
  const int c   = c0 + tid;
  const int b   = blockIdx.z;
  const int t0  = blockIdx.x * 128;
  const float w0 = conv_w[c * 4 + 0], w1 = conv_w[c * 4 + 1];
  const float w2 = conv_w[c * 4 + 2], w3 = conv_w[c * 4 + 3];
  const float cb = conv_b[c], Dp = Dp_[c];
  const long mb = (long)b * SEQ;

  float xm3 = 0.f, xm2 = 0.f, xm1 = 0.f, h = 0.f;
  const int ts = t0 - WARM;   // panel-0 start; < 0 only for blockIdx.x==0
  if (t0 > 0) {
    xm3 = (float)xz[(mb + ts - 3) * (long)NXZ + c];
    xm2 = (float)xz[(mb + ts - 2) * (long)NXZ + c];
    xm1 = (float)xz[(mb + ts - 1) * (long)NXZ + c];
  }

  for (int p = 0; p < 3; ++p) {
    const int tp = ts + p * 64;         // block-uniform
    __syncthreads();                    // protect previous panel before overwrite
    if (tp >= 0) {
#pragma unroll
      for (int j = 0; j < 8; ++j) {
        const int idx = j * 256 + tid, row = idx >> 5, col = (idx & 31) << 3;
        *(v8h*)&xs[row][col] = *(const v8h*)&xz[(mb + tp + row) * (long)NXZ + c0 + col];
      }
      if (p > 0) {
#pragma unroll
        for (int j = 0; j < 8; ++j) {
          const int idx = j * 256 + tid, row = idx >> 5, col = (idx & 31) << 3;
          *(v8h*)&zs[row][col] = *(const v8h*)&xz[(mb + tp + row) * (long)NXZ + D_INNER + c0 + col];
        }
      }
    }
    __syncthreads();
    if (tp < 0) continue;               // t<0: zero left-pad, h stays 0 (skip)
    if (p == 0) {
      // warm-up: EMA only, no output
      for (int tl = 0; tl < 64; ++tl) {
        float xt = (float)xs[tl][tid];
        float u = w0 * xm3 + w1 * xm2 + w2 * xm1 + w3 * xt + cb;
        h = 0.9f * h + 0.1f * (u / (1.f + __expf(-u)));
        xm3 = xm2; xm2 = xm1; xm1 = xt;
      }
    } else {
      f16* yo = y + (mb + tp) * (long)D_INNER + c;
      for (int tl = 0; tl < 64; ++tl) {
        float xt = (float)xs[tl][tid];
        float u = w0 * xm3 + w1 * xm2 + w2 * xm1 + w3 * xt + cb;
        float v = u / (1.f + __expf(-u));
        h = 0.9f * h + 0.1f * v;
        float zv = (float)zs[tl][tid];
        float g = zv / (1.f + __expf(-zv));
        yo[(long)tl * D_INNER] = (f16)((v * Dp + h) * g);
        xm3 = xm2; xm2 = xm1; xm1 = xt;
      }
    }
  }
}

// ---------------- launch ----------------
extern "C" void kernel_launch(void* const* d_in, const int* in_sizes, int n_in,
                              void* d_out, int out_size, void* d_ws, size_t ws_size,
                              hipStream_t stream) {
  const float* x       = (const float*)d_in[0];
  const float* in_w    = (const float*)d_in[1];
  const float* in_b    = (const float*)d_in[2];
  const float* conv_w  = (const float*)d_in[3];
  const float* conv_b  = (const float*)d_in[4];
  // d_in[5..8] (xp_w, xp_b, dt_w, dt_b) are dead code in the reference
  const float* D_param = (const float*)d_in[9];
  const float* out_w   = (const float*)d_in[10];
  const float* out_b   = (const float*)d_in[11];
  float* out = (float*)d_out;

  char* p = (char*)d_ws;
  f16* xb    = (f16*)p; p += (size_t)MTOT * D_MODEL * 2;   // 25.2 MB
  f16* wInT  = (f16*)p; p += (size_t)NXZ * D_MODEL * 2;    //  4.7 MB
  f16* wOutT = (f16*)p; p += (size_t)D_MODEL * D_INNER * 2;//  2.4 MB
  f16* xzb   = (f16*)p; p += (size_t)MTOT * NXZ * 2;       // 100.7 MB ([m][n])
  f16* yb    = (f16*)p; p += (size_t)MTOT * D_INNER * 2;   // 50.3 MB

  // prep
  k_cvt<<<(MTOT * D_MODEL / 4 + 255) / 256, 256, 0, stream>>>(x, xb, MTOT * D_MODEL / 4);
  k_transpose_cvt<<<dim3(NXZ / 32, D_MODEL / 32), dim3(32, 8), 0, stream>>>(in_w, wInT, D_MODEL, NXZ);
  k_transpose_cvt<<<dim3(D_MODEL / 32, D_INNER / 32), dim3(32, 8), 0, stream>>>(out_w, wOutT, D_INNER, D_MODEL);

  // xz = x @ in_w + in_b   (f16, [m][n]); grid 24 x 64 = 1536 blocks
  k_gemm_bt<true><<<dim3(NXZ / 128, MTOT / 256), 256, 0, stream>>>(xb, wInT, in_b, xzb, MTOT, NXZ, D_MODEL);

  // conv + silu + EMA scan + gate -> y (f16, [m][c])
  k_conv_scan<<<dim3(SEQ / 128, D_INNER / 256, BATCH), 256, 0, stream>>>(xzb, conv_w, conv_b, D_param, yb);

  // out = y @ out_w + out_b  (f32, [m][n]); grid 6 x 64 = 384 blocks (1 round)
  k_gemm_bt<false><<<dim3(D_MODEL / 128, MTOT / 256), 256, 0, stream>>>(yb, wOutT, out_b, out, MTOT, D_MODEL, D_INNER);
}